// Round 1
// baseline (849.435 us; speedup 1.0000x reference)
//
#include <hip/hip_runtime.h>
#include <stdint.h>

typedef unsigned int u32;
typedef unsigned short u16;

using s16x8 = __attribute__((ext_vector_type(8))) short;
using f32x4 = __attribute__((ext_vector_type(4))) float;

#define N_NODES_C 50000
#define N_EDGES_C 800000
#define N_GRAPHS_C 256
#define N_FEAT_C 128
#define N_HID_C 256

static __device__ __forceinline__ float bf2f(u16 u) {
  union { u32 u; float f; } c; c.u = ((u32)u) << 16; return c.f;
}
static __device__ __forceinline__ u16 f2bf(float f) {
  union { float f; u32 u; } c; c.f = f;
  u32 u = c.u;
  return (u16)((u + 0x7fffu + ((u >> 16) & 1u)) >> 16);
}

// ---------- converts ----------
__global__ void convt_kernel(const float* __restrict__ W, u16* __restrict__ Wt, int K, int N) {
  int idx = blockIdx.x * 256 + threadIdx.x;
  if (idx >= K * N) return;
  int n = idx / K, k = idx - n * K;
  Wt[idx] = f2bf(W[(size_t)k * N + n]);   // Wt[n][k] = W[k][n]
}

__global__ void cvt_kernel(const float* __restrict__ x, u16* __restrict__ xb, int n) {
  int idx = blockIdx.x * 256 + threadIdx.x;
  if (idx < n) xb[idx] = f2bf(x[idx]);
}

// ---------- CSR build ----------
__global__ void count_kernel(const int* __restrict__ dst, int* __restrict__ cnt, int E) {
  int e = blockIdx.x * 256 + threadIdx.x;
  if (e < E) atomicAdd(&cnt[dst[e]], 1);
}

__global__ void scan_kernel(const int* __restrict__ cnt, int* __restrict__ offs,
                            int* __restrict__ cursor, int n) {
  __shared__ int sd[1024];
  __shared__ int carry;
  if (threadIdx.x == 0) carry = 0;
  __syncthreads();
  for (int base = 0; base <= n; base += 1024) {
    int i = base + (int)threadIdx.x;
    int v = (i < n) ? cnt[i] : 0;
    sd[threadIdx.x] = v;
    __syncthreads();
    for (int off = 1; off < 1024; off <<= 1) {
      int t = (threadIdx.x >= (unsigned)off) ? sd[threadIdx.x - off] : 0;
      __syncthreads();
      sd[threadIdx.x] += t;
      __syncthreads();
    }
    int incl = sd[threadIdx.x];
    int total = sd[1023];
    int excl = incl - v + carry;
    if (i <= n) {
      offs[i] = excl;
      if (i < n) cursor[i] = excl;
    }
    __syncthreads();
    if (threadIdx.x == 0) carry += total;
    __syncthreads();
  }
}

__global__ void fill_kernel(const int* __restrict__ src, const int* __restrict__ dst,
                            int* __restrict__ cursor, int* __restrict__ csr, int E) {
  int e = blockIdx.x * 256 + threadIdx.x;
  if (e < E) {
    int p = atomicAdd(&cursor[dst[e]], 1);
    csr[p] = src[e];
  }
}

// ---------- aggregation: h = x + sum_{j in N(i)} x_j  (gather via CSR) ----------
template <int D>
__global__ __launch_bounds__(256) void agg_kernel(const u16* __restrict__ xin,
                                                  const int* __restrict__ offs,
                                                  const int* __restrict__ csr,
                                                  u16* __restrict__ hout) {
  constexpr int V = D / 64;       // feats per lane (2 or 4)
  constexpr int NW = V / 2;       // u32 words per lane
  int wid = threadIdx.x >> 6, lane = threadIdx.x & 63;
  int node = blockIdx.x * 4 + wid;
  if (node >= N_NODES_C) return;
  int f0 = lane * V;
  float acc[V];
  {
    const u32* p = reinterpret_cast<const u32*>(xin + (size_t)node * D + f0);
#pragma unroll
    for (int w = 0; w < NW; w++) {
      u32 v = p[w];
      acc[2 * w] = bf2f((u16)v);
      acc[2 * w + 1] = bf2f((u16)(v >> 16));
    }
  }
  int e1 = offs[node + 1];
  for (int e = offs[node]; e < e1; e++) {
    int s = csr[e];
    const u32* p = reinterpret_cast<const u32*>(xin + (size_t)s * D + f0);
#pragma unroll
    for (int w = 0; w < NW; w++) {
      u32 v = p[w];
      acc[2 * w] += bf2f((u16)v);
      acc[2 * w + 1] += bf2f((u16)(v >> 16));
    }
  }
  u32* q = reinterpret_cast<u32*>(hout + (size_t)node * D + f0);
#pragma unroll
  for (int w = 0; w < NW; w++)
    q[w] = (u32)f2bf(acc[2 * w]) | ((u32)f2bf(acc[2 * w + 1]) << 16);
}

// ---------- bf16 MFMA GEMM: C[M,256] = A[M,K] @ B[K,256], B given as Bt[256][K] ----------
template <int K, bool RELU, bool OUTF32>
__global__ __launch_bounds__(256) void gemm_kernel(const u16* __restrict__ A,
                                                   const u16* __restrict__ Bt,
                                                   u16* __restrict__ outB,
                                                   float* __restrict__ outF, int ldc) {
  constexpr int BM = 128, BN = 128, BK = 64, LDP = 72;  // +8 bf16 pad: 144B rows, 16B aligned
  __shared__ u16 Al[BM * LDP];
  __shared__ u16 Bl[BN * LDP];
  const int tid = threadIdx.x;
  const int wid = tid >> 6, lane = tid & 63;
  const int brow = blockIdx.x * BM;
  const int bcol = blockIdx.y * BN;
  const int wr = (wid >> 1) * 64, wc = (wid & 1) * 64;
  f32x4 acc[4][4] = {};

  for (int k0 = 0; k0 < K; k0 += BK) {
#pragma unroll
    for (int i = 0; i < 4; i++) {
      int c = tid + 256 * i;          // 1024 chunks of 16B per tile
      int r = c >> 3, co = (c & 7) * 8;
      int gr = brow + r;
      gr = gr < N_NODES_C ? gr : N_NODES_C - 1;
      uint4 v = *reinterpret_cast<const uint4*>(A + (size_t)gr * K + k0 + co);
      *reinterpret_cast<uint4*>(&Al[r * LDP + co]) = v;
      uint4 w = *reinterpret_cast<const uint4*>(Bt + (size_t)(bcol + r) * K + k0 + co);
      *reinterpret_cast<uint4*>(&Bl[r * LDP + co]) = w;
    }
    __syncthreads();
#pragma unroll
    for (int ks = 0; ks < BK; ks += 32) {
      const int kk = ks + (lane >> 4) * 8;
      s16x8 a[4], b[4];
#pragma unroll
      for (int m = 0; m < 4; m++)
        a[m] = *reinterpret_cast<const s16x8*>(&Al[(wr + m * 16 + (lane & 15)) * LDP + kk]);
#pragma unroll
      for (int n = 0; n < 4; n++)
        b[n] = *reinterpret_cast<const s16x8*>(&Bl[(wc + n * 16 + (lane & 15)) * LDP + kk]);
#pragma unroll
      for (int m = 0; m < 4; m++)
#pragma unroll
        for (int n = 0; n < 4; n++)
          acc[m][n] = __builtin_amdgcn_mfma_f32_16x16x32_bf16(a[m], b[n], acc[m][n], 0, 0, 0);
    }
    __syncthreads();
  }

  const int cbase = bcol + wc + (lane & 15);
  const int rsub = (lane >> 4) * 4;
#pragma unroll
  for (int m = 0; m < 4; m++) {
#pragma unroll
    for (int r = 0; r < 4; r++) {
      int row = brow + wr + m * 16 + rsub + r;
      if (row >= N_NODES_C) continue;
#pragma unroll
      for (int n = 0; n < 4; n++) {
        float v = acc[m][n][r];
        if (RELU) v = v > 0.f ? v : 0.f;
        int col = cbase + n * 16;
        if (OUTF32)
          outF[(size_t)row * ldc + col] = v;
        else
          outB[(size_t)row * ldc + col] = f2bf(v);
      }
    }
  }
}

// ---------- BatchNorm ----------
__global__ void stats_kernel(const float* __restrict__ c, int ldc, float* __restrict__ stats) {
  int f = threadIdx.x;
  float s = 0.f, s2 = 0.f;
  for (int r = blockIdx.x; r < N_NODES_C; r += gridDim.x) {
    float v = c[(size_t)r * ldc + f];
    s += v;
    s2 += v * v;
  }
  atomicAdd(&stats[f], s);
  atomicAdd(&stats[256 + f], s2);
}

__global__ void scalebias_kernel(const float* __restrict__ stats, const float* __restrict__ gamma,
                                 const float* __restrict__ beta, float* __restrict__ sb) {
  int f = threadIdx.x;
  const float invM = 1.0f / (float)N_NODES_C;
  float mean = stats[f] * invM;
  float var = stats[256 + f] * invM - mean * mean;
  float sc = gamma[f] * rsqrtf(var + 1e-5f);
  sb[f] = sc;
  sb[256 + f] = beta[f] - mean * sc;
}

__global__ void norm_kernel(float* __restrict__ c, int ldc, const float* __restrict__ sb,
                            u16* __restrict__ xn) {
  int idx = blockIdx.x * 256 + threadIdx.x;  // exactly N_NODES*256 threads
  int r = idx >> 8, f = idx & 255;
  float v = c[(size_t)r * ldc + f];
  float y = fmaf(v, sb[f], sb[256 + f]);
  c[(size_t)r * ldc + f] = y;
  xn[idx] = f2bf(y);
}

// ---------- global_add_pool ----------
__global__ void pool_kernel(const float* __restrict__ c, int ldc, const int* __restrict__ batch,
                            float* __restrict__ outp) {
  int idx = blockIdx.x * 256 + threadIdx.x;
  int r = idx >> 8, f = idx & 255;
  atomicAdd(&outp[(size_t)batch[r] * 256 + f], c[(size_t)r * ldc + f]);
}

extern "C" void kernel_launch(void* const* d_in, const int* in_sizes, int n_in,
                              void* d_out, int out_size, void* d_ws, size_t ws_size,
                              hipStream_t stream) {
  (void)in_sizes; (void)n_in; (void)out_size; (void)ws_size;
  const float* x = (const float*)d_in[0];
  const int* ei = (const int*)d_in[1];
  const int* batch = (const int*)d_in[2];
  const float* W1_0 = (const float*)d_in[3];
  const float* W2_0 = (const float*)d_in[4];
  const float* gamma0 = (const float*)d_in[5];
  const float* beta0 = (const float*)d_in[6];
  const float* W1_1 = (const float*)d_in[7];
  const float* W2_1 = (const float*)d_in[8];
  const float* gamma1 = (const float*)d_in[9];
  const float* beta1 = (const float*)d_in[10];
  const float* W1_2 = (const float*)d_in[11];
  const float* W2_2 = (const float*)d_in[12];

  float* out = (float*)d_out;
  float* xpool = out;                                  // [256,256]
  float* concat = out + (size_t)N_GRAPHS_C * N_HID_C;  // [50000,768]

  char* ws = (char*)d_ws;
  size_t off = 0;
  auto alloc = [&](size_t bytes) -> char* {
    char* p = ws + off;
    off = (off + bytes + 255) & ~(size_t)255;
    return p;
  };
  int* cnt = (int*)alloc((N_NODES_C + 1) * 4);
  int* offs = (int*)alloc((N_NODES_C + 1) * 4);
  int* cursor = (int*)alloc(N_NODES_C * 4);
  int* csr = (int*)alloc((size_t)N_EDGES_C * 4);
  u16* xb = (u16*)alloc((size_t)N_NODES_C * N_FEAT_C * 2);
  u16* hin = (u16*)alloc((size_t)N_NODES_C * N_HID_C * 2);
  u16* tbuf = (u16*)alloc((size_t)N_NODES_C * N_HID_C * 2);
  u16* xn = (u16*)alloc((size_t)N_NODES_C * N_HID_C * 2);
  u16* w10t = (u16*)alloc((size_t)N_FEAT_C * N_HID_C * 2);
  u16* w20t = (u16*)alloc((size_t)N_HID_C * N_HID_C * 2);
  u16* w11t = (u16*)alloc((size_t)N_HID_C * N_HID_C * 2);
  u16* w21t = (u16*)alloc((size_t)N_HID_C * N_HID_C * 2);
  u16* w12t = (u16*)alloc((size_t)N_HID_C * N_HID_C * 2);
  u16* w22t = (u16*)alloc((size_t)N_HID_C * N_HID_C * 2);
  float* stats = (float*)alloc(512 * 4);
  float* sb = (float*)alloc(512 * 4);

  const int* srcv = ei;
  const int* dstv = ei + N_EDGES_C;

  hipMemsetAsync(cnt, 0, (N_NODES_C + 1) * 4, stream);

  convt_kernel<<<(N_FEAT_C * N_HID_C + 255) / 256, 256, 0, stream>>>(W1_0, w10t, N_FEAT_C, N_HID_C);
  convt_kernel<<<(N_HID_C * N_HID_C + 255) / 256, 256, 0, stream>>>(W2_0, w20t, N_HID_C, N_HID_C);
  convt_kernel<<<(N_HID_C * N_HID_C + 255) / 256, 256, 0, stream>>>(W1_1, w11t, N_HID_C, N_HID_C);
  convt_kernel<<<(N_HID_C * N_HID_C + 255) / 256, 256, 0, stream>>>(W2_1, w21t, N_HID_C, N_HID_C);
  convt_kernel<<<(N_HID_C * N_HID_C + 255) / 256, 256, 0, stream>>>(W1_2, w12t, N_HID_C, N_HID_C);
  convt_kernel<<<(N_HID_C * N_HID_C + 255) / 256, 256, 0, stream>>>(W2_2, w22t, N_HID_C, N_HID_C);
  cvt_kernel<<<(N_NODES_C * N_FEAT_C + 255) / 256, 256, 0, stream>>>(x, xb, N_NODES_C * N_FEAT_C);

  count_kernel<<<(N_EDGES_C + 255) / 256, 256, 0, stream>>>(dstv, cnt, N_EDGES_C);
  scan_kernel<<<1, 1024, 0, stream>>>(cnt, offs, cursor, N_NODES_C);
  fill_kernel<<<(N_EDGES_C + 255) / 256, 256, 0, stream>>>(srcv, dstv, cursor, csr, N_EDGES_C);

  dim3 ggrid((N_NODES_C + 127) / 128, 2);
  const int nblk = (N_NODES_C * N_HID_C) / 256;  // 50000

  // ---- Layer 0 ----
  agg_kernel<128><<<(N_NODES_C + 3) / 4, 256, 0, stream>>>(xb, offs, csr, hin);
  gemm_kernel<128, true, false><<<ggrid, 256, 0, stream>>>(hin, w10t, tbuf, nullptr, N_HID_C);
  gemm_kernel<256, true, true><<<ggrid, 256, 0, stream>>>(tbuf, w20t, nullptr, concat + 0, 768);
  hipMemsetAsync(stats, 0, 512 * 4, stream);
  stats_kernel<<<256, 256, 0, stream>>>(concat + 0, 768, stats);
  scalebias_kernel<<<1, 256, 0, stream>>>(stats, gamma0, beta0, sb);
  norm_kernel<<<nblk, 256, 0, stream>>>(concat + 0, 768, sb, xn);

  // ---- Layer 1 ----
  agg_kernel<256><<<(N_NODES_C + 3) / 4, 256, 0, stream>>>(xn, offs, csr, hin);
  gemm_kernel<256, true, false><<<ggrid, 256, 0, stream>>>(hin, w11t, tbuf, nullptr, N_HID_C);
  gemm_kernel<256, true, true><<<ggrid, 256, 0, stream>>>(tbuf, w21t, nullptr, concat + 256, 768);
  hipMemsetAsync(stats, 0, 512 * 4, stream);
  stats_kernel<<<256, 256, 0, stream>>>(concat + 256, 768, stats);
  scalebias_kernel<<<1, 256, 0, stream>>>(stats, gamma1, beta1, sb);
  norm_kernel<<<nblk, 256, 0, stream>>>(concat + 256, 768, sb, xn);

  // ---- Layer 2 (no relu, no BN) ----
  agg_kernel<256><<<(N_NODES_C + 3) / 4, 256, 0, stream>>>(xn, offs, csr, hin);
  gemm_kernel<256, true, false><<<ggrid, 256, 0, stream>>>(hin, w12t, tbuf, nullptr, N_HID_C);
  gemm_kernel<256, false, true><<<ggrid, 256, 0, stream>>>(tbuf, w22t, nullptr, concat + 512, 768);

  // ---- pool ----
  hipMemsetAsync(xpool, 0, (size_t)N_GRAPHS_C * N_HID_C * 4, stream);
  pool_kernel<<<nblk, 256, 0, stream>>>(concat + 512, 768, batch, xpool);
}

// Round 2
// 498.905 us; speedup vs baseline: 1.7026x; 1.7026x over previous
//
#include <hip/hip_runtime.h>
#include <stdint.h>

typedef unsigned int u32;
typedef unsigned short u16;

using s16x8 = __attribute__((ext_vector_type(8))) short;
using f32x4 = __attribute__((ext_vector_type(4))) float;

#define N_NODES_C 50000
#define N_EDGES_C 800000
#define N_GRAPHS_C 256
#define N_FEAT_C 128
#define N_HID_C 256

static __device__ __forceinline__ float bf2f(u16 u) {
  union { u32 u; float f; } c; c.u = ((u32)u) << 16; return c.f;
}
static __device__ __forceinline__ u16 f2bf(float f) {
  union { float f; u32 u; } c; c.f = f;
  u32 u = c.u;
  return (u16)((u + 0x7fffu + ((u >> 16) & 1u)) >> 16);
}

static __device__ __forceinline__ void gload_lds16(const u16* g, u16* l) {
  __builtin_amdgcn_global_load_lds(
      (const __attribute__((address_space(1))) unsigned int*)g,
      (__attribute__((address_space(3))) unsigned int*)l, 16, 0, 0);
}

// ---------- converts ----------
__global__ void convt_all_kernel(const float* __restrict__ Wa, const float* __restrict__ Wb,
                                 const float* __restrict__ Wc, const float* __restrict__ Wd,
                                 const float* __restrict__ We, const float* __restrict__ Wf,
                                 u16* oa, u16* ob, u16* oc, u16* od, u16* oe, u16* of_) {
  int m = blockIdx.y;
  const float* W; u16* o; int K;
  switch (m) {
    case 0: W = Wa; o = oa; K = 128; break;
    case 1: W = Wb; o = ob; K = 256; break;
    case 2: W = Wc; o = oc; K = 256; break;
    case 3: W = Wd; o = od; K = 256; break;
    case 4: W = We; o = oe; K = 256; break;
    default: W = Wf; o = of_; K = 256; break;
  }
  int idx = blockIdx.x * 256 + threadIdx.x;
  if (idx >= K * 256) return;
  int n = idx / K, k = idx - n * K;
  o[idx] = f2bf(W[(size_t)k * 256 + n]);  // o[n][k] = W[k][n]
}

__global__ void cvt_kernel(const float* __restrict__ x, u16* __restrict__ xb, int n) {
  int idx = blockIdx.x * 256 + threadIdx.x;
  if (idx < n) xb[idx] = f2bf(x[idx]);
}

// ---------- CSR build ----------
__global__ void count_kernel(const int* __restrict__ dst, int* __restrict__ cnt, int E) {
  int e = blockIdx.x * 256 + threadIdx.x;
  if (e < E) atomicAdd(&cnt[dst[e]], 1);
}

// phase A: per-block inclusive scan of 1024 elements + block totals
__global__ void scanA_kernel(const int* __restrict__ cnt, int* __restrict__ incl,
                             int* __restrict__ bsum, int n) {
  __shared__ int sd[1024];
  int i = blockIdx.x * 1024 + (int)threadIdx.x;
  int v = (i < n) ? cnt[i] : 0;
  sd[threadIdx.x] = v;
  __syncthreads();
  for (int off = 1; off < 1024; off <<= 1) {
    int t = ((int)threadIdx.x >= off) ? sd[threadIdx.x - off] : 0;
    __syncthreads();
    sd[threadIdx.x] += t;
    __syncthreads();
  }
  if (i < n) incl[i] = sd[threadIdx.x];
  if (threadIdx.x == 1023) bsum[blockIdx.x] = sd[1023];
}

// phase B: exclusive scan of block sums (small, serial)
__global__ void scanB_kernel(int* bsum, int nb) {
  if (threadIdx.x == 0) {
    int s = 0;
    for (int b = 0; b < nb; b++) { int t = bsum[b]; bsum[b] = s; s += t; }
  }
}

// phase C: combine -> exclusive offsets + cursor
__global__ void scanC_kernel(const int* __restrict__ cnt, const int* __restrict__ incl,
                             const int* __restrict__ bsum, int* __restrict__ offs,
                             int* __restrict__ cursor, int n) {
  int i = blockIdx.x * 1024 + (int)threadIdx.x;
  if (i < n) {
    int e = incl[i] - cnt[i] + bsum[blockIdx.x];
    offs[i] = e;
    cursor[i] = e;
  }
  if (i == 0) offs[n] = N_EDGES_C;
}

__global__ void fill_kernel(const int* __restrict__ src, const int* __restrict__ dst,
                            int* __restrict__ cursor, int* __restrict__ csr, int E) {
  int e = blockIdx.x * 256 + threadIdx.x;
  if (e < E) {
    int p = atomicAdd(&cursor[dst[e]], 1);
    csr[p] = src[e];
  }
}

// ---------- aggregation: h = x + sum_{j in N(i)} x_j ----------
// wave per node; lanes split into EPW edge-slots, each slot loads 16B (8 feats)
template <int D>
__global__ __launch_bounds__(256) void agg_kernel(const u16* __restrict__ xin,
                                                  const int* __restrict__ offs,
                                                  const int* __restrict__ csr,
                                                  u16* __restrict__ hout) {
  constexpr int LPE = D / 8;       // lanes per edge (16 or 32)
  constexpr int EPW = 64 / LPE;    // edge slots per wave (4 or 2)
  int wid = threadIdx.x >> 6, lane = threadIdx.x & 63;
  int node = blockIdx.x * 4 + wid;
  if (node >= N_NODES_C) return;
  int sub = lane / LPE;
  int fl = lane % LPE;
  int f0 = fl * 8;
  float acc[8];
  if (sub == 0) {
    uint4 v = *reinterpret_cast<const uint4*>(xin + (size_t)node * D + f0);
    const u32* pv = reinterpret_cast<const u32*>(&v);
#pragma unroll
    for (int t = 0; t < 4; t++) {
      acc[2 * t] = bf2f((u16)pv[t]);
      acc[2 * t + 1] = bf2f((u16)(pv[t] >> 16));
    }
  } else {
#pragma unroll
    for (int t = 0; t < 8; t++) acc[t] = 0.f;
  }
  int e1 = offs[node + 1];
  for (int e = offs[node] + sub; e < e1; e += EPW) {
    int s = csr[e];
    uint4 v = *reinterpret_cast<const uint4*>(xin + (size_t)s * D + f0);
    const u32* pv = reinterpret_cast<const u32*>(&v);
#pragma unroll
    for (int t = 0; t < 4; t++) {
      acc[2 * t] += bf2f((u16)pv[t]);
      acc[2 * t + 1] += bf2f((u16)(pv[t] >> 16));
    }
  }
#pragma unroll
  for (int j = 0; j < 8; j++) {
    if (EPW == 4) acc[j] += __shfl_xor(acc[j], 16, 64);
    acc[j] += __shfl_xor(acc[j], 32, 64);
  }
  if (sub == 0) {
    u32 w[4];
#pragma unroll
    for (int t = 0; t < 4; t++)
      w[t] = (u32)f2bf(acc[2 * t]) | ((u32)f2bf(acc[2 * t + 1]) << 16);
    *reinterpret_cast<uint4*>(hout + (size_t)node * D + f0) =
        *reinterpret_cast<const uint4*>(w);
  }
}

// ---------- bf16 MFMA GEMM (m97-style: global_load_lds + XOR-swizzled source) ----------
// C[M,256] = A[M,K] @ B[K,256]; B given transposed Bt[256][K]
template <int K, bool RELU, bool OUTF32, bool STATS>
__global__ __launch_bounds__(256) void gemm_kernel(const u16* __restrict__ A,
                                                   const u16* __restrict__ Bt,
                                                   u16* __restrict__ outB,
                                                   float* __restrict__ outF, int ldc,
                                                   float* __restrict__ statsp) {
  constexpr int BM = 128, BN = 128, BK = 64;
  __shared__ u16 Al[BM * BK];   // linear [128][64], 128B rows, XOR-swizzled contents
  __shared__ u16 Bl[BN * BK];
  const int tid = threadIdx.x;
  const int wid = tid >> 6, lane = tid & 63;
  const int brow = blockIdx.x * BM;
  const int bcol = blockIdx.y * BN;
  const int wr = (wid >> 1) * 64, wc = (wid & 1) * 64;
  f32x4 acc[4][4] = {};

  const int lrow = lane >> 3;                 // row within 8-row chunk
  const int lw = lane & 7;                    // 16B slot within row
  const int colA = ((lw ^ lrow) * 8);         // pre-swizzled global column (u16)
  const int sw = (lane & 7) << 3;             // read-side XOR (u16), row&7 == lane&7

  for (int k0 = 0; k0 < K; k0 += BK) {
#pragma unroll
    for (int i = 0; i < 4; i++) {
      int c = wid * 4 + i;                    // chunk 0..15, 1KB each
      int r = c * 8 + lrow;
      int gr = brow + r;
      gr = gr < N_NODES_C ? gr : N_NODES_C - 1;
      gload_lds16(A + (size_t)gr * K + k0 + colA, &Al[c * 512]);
      gload_lds16(Bt + (size_t)(bcol + r) * K + k0 + colA, &Bl[c * 512]);
    }
    __syncthreads();
#pragma unroll
    for (int ks = 0; ks < BK; ks += 32) {
      const int kk = ks + (lane >> 4) * 8;
      const int ki = kk ^ sw;
      s16x8 a[4], b[4];
#pragma unroll
      for (int m = 0; m < 4; m++)
        a[m] = *reinterpret_cast<const s16x8*>(&Al[(wr + m * 16 + (lane & 15)) * 64 + ki]);
#pragma unroll
      for (int n = 0; n < 4; n++)
        b[n] = *reinterpret_cast<const s16x8*>(&Bl[(wc + n * 16 + (lane & 15)) * 64 + ki]);
#pragma unroll
      for (int m = 0; m < 4; m++)
#pragma unroll
        for (int n = 0; n < 4; n++)
          acc[m][n] = __builtin_amdgcn_mfma_f32_16x16x32_bf16(a[m], b[n], acc[m][n], 0, 0, 0);
    }
    __syncthreads();
  }

  const int cb = bcol + wc + (lane & 15);
  const int rsub = (lane >> 4) * 4;
  float s1[4] = {0.f, 0.f, 0.f, 0.f}, s2[4] = {0.f, 0.f, 0.f, 0.f};
#pragma unroll
  for (int m = 0; m < 4; m++) {
#pragma unroll
    for (int r = 0; r < 4; r++) {
      int row = brow + wr + m * 16 + rsub + r;
      if (row >= N_NODES_C) continue;
#pragma unroll
      for (int n = 0; n < 4; n++) {
        float v = acc[m][n][r];
        if (RELU) v = v > 0.f ? v : 0.f;
        int col = cb + n * 16;
        if (OUTF32)
          outF[(size_t)row * ldc + col] = v;
        else
          outB[(size_t)row * ldc + col] = f2bf(v);
        if (STATS) { s1[n] += v; s2[n] += v * v; }
      }
    }
  }
  if (STATS) {
#pragma unroll
    for (int n = 0; n < 4; n++) {
      float a0 = s1[n], b0 = s2[n];
      a0 += __shfl_xor(a0, 16, 64);
      b0 += __shfl_xor(b0, 16, 64);
      a0 += __shfl_xor(a0, 32, 64);
      b0 += __shfl_xor(b0, 32, 64);
      if (lane < 16) {
        atomicAdd(&statsp[cb + n * 16], a0);
        atomicAdd(&statsp[256 + cb + n * 16], b0);
      }
    }
  }
}

// ---------- BatchNorm scale/bias ----------
__global__ void scalebias_kernel(const float* __restrict__ stats, const float* __restrict__ gamma,
                                 const float* __restrict__ beta, float* __restrict__ sb) {
  int f = threadIdx.x;
  const float invM = 1.0f / (float)N_NODES_C;
  float mean = stats[f] * invM;
  float var = stats[256 + f] * invM - mean * mean;
  float sc = gamma[f] * rsqrtf(var + 1e-5f);
  sb[f] = sc;
  sb[256 + f] = beta[f] - mean * sc;
}

__global__ __launch_bounds__(256) void norm_kernel(float* __restrict__ c, int ldc,
                                                   const float* __restrict__ sb,
                                                   u16* __restrict__ xn) {
  int f = threadIdx.x;
  float sc = sb[f], bi = sb[256 + f];
  for (int r = blockIdx.x; r < N_NODES_C; r += gridDim.x) {
    size_t idx = (size_t)r * ldc + f;
    float y = fmaf(c[idx], sc, bi);
    c[idx] = y;
    xn[(size_t)r * 256 + f] = f2bf(y);
  }
}

// ---------- global_add_pool (batch is sorted -> per-graph segments) ----------
__global__ __launch_bounds__(256) void pool_kernel(const float* __restrict__ c, int ldc,
                                                   const int* __restrict__ batch,
                                                   float* __restrict__ outp) {
  __shared__ float red[1024];
  int g = blockIdx.x;
  int wid = threadIdx.x >> 6, lane = threadIdx.x & 63;
  int lo = 0, hi = N_NODES_C;
  while (lo < hi) { int mid = (lo + hi) >> 1; if (batch[mid] < g) lo = mid + 1; else hi = mid; }
  int start = lo;
  hi = N_NODES_C;
  while (lo < hi) { int mid = (lo + hi) >> 1; if (batch[mid] <= g) lo = mid + 1; else hi = mid; }
  int end = lo;
  float acc[4] = {0.f, 0.f, 0.f, 0.f};
  for (int r = start + wid; r < end; r += 4) {
    float4 v = *reinterpret_cast<const float4*>(c + (size_t)r * ldc + lane * 4);
    acc[0] += v.x; acc[1] += v.y; acc[2] += v.z; acc[3] += v.w;
  }
#pragma unroll
  for (int j = 0; j < 4; j++) red[wid * 256 + lane * 4 + j] = acc[j];
  __syncthreads();
  int f = threadIdx.x;
  float s = red[f] + red[256 + f] + red[512 + f] + red[768 + f];
  outp[(size_t)g * 256 + f] = s;
}

extern "C" void kernel_launch(void* const* d_in, const int* in_sizes, int n_in,
                              void* d_out, int out_size, void* d_ws, size_t ws_size,
                              hipStream_t stream) {
  (void)in_sizes; (void)n_in; (void)out_size; (void)ws_size;
  const float* x = (const float*)d_in[0];
  const int* ei = (const int*)d_in[1];
  const int* batch = (const int*)d_in[2];
  const float* W1_0 = (const float*)d_in[3];
  const float* W2_0 = (const float*)d_in[4];
  const float* gamma0 = (const float*)d_in[5];
  const float* beta0 = (const float*)d_in[6];
  const float* W1_1 = (const float*)d_in[7];
  const float* W2_1 = (const float*)d_in[8];
  const float* gamma1 = (const float*)d_in[9];
  const float* beta1 = (const float*)d_in[10];
  const float* W1_2 = (const float*)d_in[11];
  const float* W2_2 = (const float*)d_in[12];

  float* out = (float*)d_out;
  float* xpool = out;                                  // [256,256]
  float* concat = out + (size_t)N_GRAPHS_C * N_HID_C;  // [50000,768]

  char* ws = (char*)d_ws;
  size_t off = 0;
  auto alloc = [&](size_t bytes) -> char* {
    char* p = ws + off;
    off = (off + bytes + 255) & ~(size_t)255;
    return p;
  };
  int* cnt = (int*)alloc((N_NODES_C + 1) * 4);
  int* offs = (int*)alloc((N_NODES_C + 1) * 4);
  int* cursor = (int*)alloc(N_NODES_C * 4);
  int* incl = (int*)alloc(N_NODES_C * 4);
  int* bsum = (int*)alloc(64 * 4);
  int* csr = (int*)alloc((size_t)N_EDGES_C * 4);
  u16* xb = (u16*)alloc((size_t)N_NODES_C * N_FEAT_C * 2);
  u16* hin = (u16*)alloc((size_t)N_NODES_C * N_HID_C * 2);
  u16* tbuf = (u16*)alloc((size_t)N_NODES_C * N_HID_C * 2);
  u16* xn = (u16*)alloc((size_t)N_NODES_C * N_HID_C * 2);
  u16* w10t = (u16*)alloc((size_t)N_FEAT_C * N_HID_C * 2);
  u16* w20t = (u16*)alloc((size_t)N_HID_C * N_HID_C * 2);
  u16* w11t = (u16*)alloc((size_t)N_HID_C * N_HID_C * 2);
  u16* w21t = (u16*)alloc((size_t)N_HID_C * N_HID_C * 2);
  u16* w12t = (u16*)alloc((size_t)N_HID_C * N_HID_C * 2);
  u16* w22t = (u16*)alloc((size_t)N_HID_C * N_HID_C * 2);
  float* stats = (float*)alloc(512 * 4);
  float* sb = (float*)alloc(512 * 4);

  const int* srcv = ei;
  const int* dstv = ei + N_EDGES_C;
  const int nb = (N_NODES_C + 1023) / 1024;  // 49

  hipMemsetAsync(cnt, 0, (N_NODES_C + 1) * 4, stream);

  convt_all_kernel<<<dim3(256, 6), 256, 0, stream>>>(W1_0, W2_0, W1_1, W2_1, W1_2, W2_2,
                                                     w10t, w20t, w11t, w21t, w12t, w22t);
  cvt_kernel<<<(N_NODES_C * N_FEAT_C + 255) / 256, 256, 0, stream>>>(x, xb, N_NODES_C * N_FEAT_C);

  count_kernel<<<(N_EDGES_C + 255) / 256, 256, 0, stream>>>(dstv, cnt, N_EDGES_C);
  scanA_kernel<<<nb, 1024, 0, stream>>>(cnt, incl, bsum, N_NODES_C);
  scanB_kernel<<<1, 64, 0, stream>>>(bsum, nb);
  scanC_kernel<<<nb, 1024, 0, stream>>>(cnt, incl, bsum, offs, cursor, N_NODES_C);
  fill_kernel<<<(N_EDGES_C + 255) / 256, 256, 0, stream>>>(srcv, dstv, cursor, csr, N_EDGES_C);

  dim3 ggrid((N_NODES_C + 127) / 128, 2);

  // ---- Layer 0 ----
  agg_kernel<128><<<(N_NODES_C + 3) / 4, 256, 0, stream>>>(xb, offs, csr, hin);
  gemm_kernel<128, true, false, false><<<ggrid, 256, 0, stream>>>(hin, w10t, tbuf, nullptr, N_HID_C, nullptr);
  hipMemsetAsync(stats, 0, 512 * 4, stream);
  gemm_kernel<256, true, true, true><<<ggrid, 256, 0, stream>>>(tbuf, w20t, nullptr, concat + 0, 768, stats);
  scalebias_kernel<<<1, 256, 0, stream>>>(stats, gamma0, beta0, sb);
  norm_kernel<<<2048, 256, 0, stream>>>(concat + 0, 768, sb, xn);

  // ---- Layer 1 ----
  agg_kernel<256><<<(N_NODES_C + 3) / 4, 256, 0, stream>>>(xn, offs, csr, hin);
  gemm_kernel<256, true, false, false><<<ggrid, 256, 0, stream>>>(hin, w11t, tbuf, nullptr, N_HID_C, nullptr);
  hipMemsetAsync(stats, 0, 512 * 4, stream);
  gemm_kernel<256, true, true, true><<<ggrid, 256, 0, stream>>>(tbuf, w21t, nullptr, concat + 256, 768, stats);
  scalebias_kernel<<<1, 256, 0, stream>>>(stats, gamma1, beta1, sb);
  norm_kernel<<<2048, 256, 0, stream>>>(concat + 256, 768, sb, xn);

  // ---- Layer 2 (no relu, no BN) ----
  agg_kernel<256><<<(N_NODES_C + 3) / 4, 256, 0, stream>>>(xn, offs, csr, hin);
  gemm_kernel<256, true, false, false><<<ggrid, 256, 0, stream>>>(hin, w12t, tbuf, nullptr, N_HID_C, nullptr);
  gemm_kernel<256, false, true, false><<<ggrid, 256, 0, stream>>>(tbuf, w22t, nullptr, concat + 512, 768, nullptr);

  // ---- pool ----
  pool_kernel<<<N_GRAPHS_C, 256, 0, stream>>>(concat + 512, 768, batch, xpool);
}

// Round 3
// 467.453 us; speedup vs baseline: 1.8172x; 1.0673x over previous
//
#include <hip/hip_runtime.h>
#include <stdint.h>

typedef unsigned int u32;
typedef unsigned short u16;

using s16x8 = __attribute__((ext_vector_type(8))) short;
using f32x4 = __attribute__((ext_vector_type(4))) float;

#define N_NODES_C 50000
#define N_EDGES_C 800000
#define N_GRAPHS_C 256
#define N_FEAT_C 128
#define N_HID_C 256

static __device__ __forceinline__ float bf2f(u16 u) {
  union { u32 u; float f; } c; c.u = ((u32)u) << 16; return c.f;
}
static __device__ __forceinline__ u16 f2bf(float f) {
  union { float f; u32 u; } c; c.f = f;
  u32 u = c.u;
  return (u16)((u + 0x7fffu + ((u >> 16) & 1u)) >> 16);
}

static __device__ __forceinline__ void gload_lds16(const u16* g, u16* l) {
  __builtin_amdgcn_global_load_lds(
      (const __attribute__((address_space(1))) unsigned int*)g,
      (__attribute__((address_space(3))) unsigned int*)l, 16, 0, 0);
}

// ---------- converts ----------
__global__ void convt_all_kernel(const float* __restrict__ Wa, const float* __restrict__ Wb,
                                 const float* __restrict__ Wc, const float* __restrict__ Wd,
                                 const float* __restrict__ We, const float* __restrict__ Wf,
                                 u16* oa, u16* ob, u16* oc, u16* od, u16* oe, u16* of_) {
  int m = blockIdx.y;
  const float* W; u16* o; int K;
  switch (m) {
    case 0: W = Wa; o = oa; K = 128; break;
    case 1: W = Wb; o = ob; K = 256; break;
    case 2: W = Wc; o = oc; K = 256; break;
    case 3: W = Wd; o = od; K = 256; break;
    case 4: W = We; o = oe; K = 256; break;
    default: W = Wf; o = of_; K = 256; break;
  }
  int idx = blockIdx.x * 256 + threadIdx.x;
  if (idx >= K * 256) return;
  int n = idx / K, k = idx - n * K;
  o[idx] = f2bf(W[(size_t)k * 256 + n]);  // o[n][k] = W[k][n]
}

__global__ void cvt4_kernel(const float* __restrict__ x, u16* __restrict__ xb, int n4) {
  int idx = blockIdx.x * 256 + threadIdx.x;
  if (idx >= n4) return;
  float4 v = reinterpret_cast<const float4*>(x)[idx];
  u32 lo = (u32)f2bf(v.x) | ((u32)f2bf(v.y) << 16);
  u32 hi = (u32)f2bf(v.z) | ((u32)f2bf(v.w) << 16);
  uint2 w; w.x = lo; w.y = hi;
  reinterpret_cast<uint2*>(xb)[idx] = w;
}

// ---------- CSR build ----------
__global__ void count_kernel(const int* __restrict__ dst, int* __restrict__ cnt, int E) {
  int e = blockIdx.x * 256 + threadIdx.x;
  if (e < E) atomicAdd(&cnt[dst[e]], 1);
}

__global__ void scanA_kernel(const int* __restrict__ cnt, int* __restrict__ incl,
                             int* __restrict__ bsum, int n) {
  __shared__ int sd[1024];
  int i = blockIdx.x * 1024 + (int)threadIdx.x;
  int v = (i < n) ? cnt[i] : 0;
  sd[threadIdx.x] = v;
  __syncthreads();
  for (int off = 1; off < 1024; off <<= 1) {
    int t = ((int)threadIdx.x >= off) ? sd[threadIdx.x - off] : 0;
    __syncthreads();
    sd[threadIdx.x] += t;
    __syncthreads();
  }
  if (i < n) incl[i] = sd[threadIdx.x];
  if (threadIdx.x == 1023) bsum[blockIdx.x] = sd[1023];
}

__global__ void scanB_kernel(int* bsum, int nb) {
  if (threadIdx.x == 0) {
    int s = 0;
    for (int b = 0; b < nb; b++) { int t = bsum[b]; bsum[b] = s; s += t; }
  }
}

__global__ void scanC_kernel(const int* __restrict__ cnt, const int* __restrict__ incl,
                             const int* __restrict__ bsum, int* __restrict__ offs,
                             int* __restrict__ cursor, int n) {
  int i = blockIdx.x * 1024 + (int)threadIdx.x;
  if (i < n) {
    int e = incl[i] - cnt[i] + bsum[blockIdx.x];
    offs[i] = e;
    cursor[i] = e;
  }
  if (i == 0) offs[n] = N_EDGES_C;
}

__global__ void fill_kernel(const int* __restrict__ src, const int* __restrict__ dst,
                            int* __restrict__ cursor, int* __restrict__ csr, int E) {
  int e = blockIdx.x * 256 + threadIdx.x;
  if (e < E) {
    int p = atomicAdd(&cursor[dst[e]], 1);
    csr[p] = src[e];
  }
}

// ---------- aggregation: h = x + sum_{j in N(i)} x_j ----------
template <int D>
__global__ __launch_bounds__(256) void agg_kernel(const u16* __restrict__ xin,
                                                  const int* __restrict__ offs,
                                                  const int* __restrict__ csr,
                                                  u16* __restrict__ hout) {
  constexpr int LPE = D / 8;       // lanes per edge (16 or 32)
  constexpr int EPW = 64 / LPE;    // edge slots per wave (4 or 2)
  int wid = threadIdx.x >> 6, lane = threadIdx.x & 63;
  int node = blockIdx.x * 4 + wid;
  if (node >= N_NODES_C) return;
  int sub = lane / LPE;
  int fl = lane % LPE;
  int f0 = fl * 8;
  float acc[8];
  if (sub == 0) {
    uint4 v = *reinterpret_cast<const uint4*>(xin + (size_t)node * D + f0);
    const u32* pv = reinterpret_cast<const u32*>(&v);
#pragma unroll
    for (int t = 0; t < 4; t++) {
      acc[2 * t] = bf2f((u16)pv[t]);
      acc[2 * t + 1] = bf2f((u16)(pv[t] >> 16));
    }
  } else {
#pragma unroll
    for (int t = 0; t < 8; t++) acc[t] = 0.f;
  }
  int e = offs[node] + sub;
  int e1 = offs[node + 1];
  for (; e + EPW < e1; e += 2 * EPW) {
    int s0 = csr[e];
    int s1 = csr[e + EPW];
    uint4 v0 = *reinterpret_cast<const uint4*>(xin + (size_t)s0 * D + f0);
    uint4 v1 = *reinterpret_cast<const uint4*>(xin + (size_t)s1 * D + f0);
    const u32* p0 = reinterpret_cast<const u32*>(&v0);
    const u32* p1 = reinterpret_cast<const u32*>(&v1);
#pragma unroll
    for (int t = 0; t < 4; t++) {
      acc[2 * t] += bf2f((u16)p0[t]) + bf2f((u16)p1[t]);
      acc[2 * t + 1] += bf2f((u16)(p0[t] >> 16)) + bf2f((u16)(p1[t] >> 16));
    }
  }
  if (e < e1) {
    int s = csr[e];
    uint4 v = *reinterpret_cast<const uint4*>(xin + (size_t)s * D + f0);
    const u32* pv = reinterpret_cast<const u32*>(&v);
#pragma unroll
    for (int t = 0; t < 4; t++) {
      acc[2 * t] += bf2f((u16)pv[t]);
      acc[2 * t + 1] += bf2f((u16)(pv[t] >> 16));
    }
  }
#pragma unroll
  for (int j = 0; j < 8; j++) {
    if (EPW == 4) acc[j] += __shfl_xor(acc[j], 16, 64);
    acc[j] += __shfl_xor(acc[j], 32, 64);
  }
  if (sub == 0) {
    u32 w[4];
#pragma unroll
    for (int t = 0; t < 4; t++)
      w[t] = (u32)f2bf(acc[2 * t]) | ((u32)f2bf(acc[2 * t + 1]) << 16);
    *reinterpret_cast<uint4*>(hout + (size_t)node * D + f0) =
        *reinterpret_cast<const uint4*>(w);
  }
}

// ---------- bf16 MFMA GEMM: C[M,256] = A[M,K] @ B[K,256]; Bt[256][K] ----------
// 512 threads, 8 waves; BM=128, BN=256 (full width), BK=64.
template <int K, bool RELU, bool OUTF32, bool STATS>
__global__ __launch_bounds__(512, 2) void gemm_kernel(const u16* __restrict__ A,
                                                      const u16* __restrict__ Bt,
                                                      u16* __restrict__ outB,
                                                      float* __restrict__ outF, int ldc,
                                                      float* __restrict__ statsp) {
  constexpr int BM = 128, BK = 64;
  __shared__ u16 Al[BM * BK];    // 16 KB, linear rows of 128B, XOR-swizzled contents
  __shared__ u16 Bl[256 * BK];   // 32 KB
  const int tid = threadIdx.x;
  const int wid = tid >> 6, lane = tid & 63;
  const int brow = blockIdx.x * BM;
  const int wr = (wid >> 2) * 64;   // 0 / 64
  const int wc = (wid & 3) * 64;    // 0 / 64 / 128 / 192
  f32x4 acc[4][4] = {};

  const int lrow = lane >> 3;            // row within 8-row chunk
  const int lw = lane & 7;               // 16B slot within 128B row
  const int colA = (lw ^ lrow) * 8;      // pre-swizzled global column (u16 units)
  const int sw = (lane & 7) << 3;        // read-side XOR (row&7 == lane&7 at read)

  for (int k0 = 0; k0 < K; k0 += BK) {
#pragma unroll
    for (int i = 0; i < 6; i++) {
      int c = wid * 6 + i;               // 48 chunks of 1KB: 16 for A, 32 for B
      if (c < 16) {
        int r = c * 8 + lrow;
        int gr = brow + r;
        gr = gr < N_NODES_C ? gr : N_NODES_C - 1;
        gload_lds16(A + (size_t)gr * K + k0 + colA, &Al[c * 512]);
      } else {
        int cc = c - 16;
        int r = cc * 8 + lrow;           // output column index (row of Bt)
        gload_lds16(Bt + (size_t)r * K + k0 + colA, &Bl[cc * 512]);
      }
    }
    __syncthreads();
#pragma unroll
    for (int ks = 0; ks < BK; ks += 32) {
      const int kk = ks + (lane >> 4) * 8;
      const int ki = kk ^ sw;
      s16x8 a[4], b[4];
#pragma unroll
      for (int m = 0; m < 4; m++)
        a[m] = *reinterpret_cast<const s16x8*>(&Al[(wr + m * 16 + (lane & 15)) * 64 + ki]);
#pragma unroll
      for (int n = 0; n < 4; n++)
        b[n] = *reinterpret_cast<const s16x8*>(&Bl[(wc + n * 16 + (lane & 15)) * 64 + ki]);
#pragma unroll
      for (int m = 0; m < 4; m++)
#pragma unroll
        for (int n = 0; n < 4; n++)
          acc[m][n] = __builtin_amdgcn_mfma_f32_16x16x32_bf16(a[m], b[n], acc[m][n], 0, 0, 0);
    }
    __syncthreads();
  }

  const int cb = wc + (lane & 15);
  const int rsub = (lane >> 4) * 4;
  float s1[4] = {0.f, 0.f, 0.f, 0.f}, s2[4] = {0.f, 0.f, 0.f, 0.f};
#pragma unroll
  for (int m = 0; m < 4; m++) {
#pragma unroll
    for (int r = 0; r < 4; r++) {
      int row = brow + wr + m * 16 + rsub + r;
      if (row >= N_NODES_C) continue;
#pragma unroll
      for (int n = 0; n < 4; n++) {
        float v = acc[m][n][r];
        if (RELU) v = v > 0.f ? v : 0.f;
        int col = cb + n * 16;
        if (OUTF32)
          outF[(size_t)row * ldc + col] = v;
        else
          outB[(size_t)row * ldc + col] = f2bf(v);
        if (STATS) { s1[n] += v; s2[n] += v * v; }
      }
    }
  }
  if (STATS) {
#pragma unroll
    for (int n = 0; n < 4; n++) {
      float a0 = s1[n], b0 = s2[n];
      a0 += __shfl_xor(a0, 16, 64);
      b0 += __shfl_xor(b0, 16, 64);
      a0 += __shfl_xor(a0, 32, 64);
      b0 += __shfl_xor(b0, 32, 64);
      if (lane < 16) {
        atomicAdd(&statsp[cb + n * 16], a0);
        atomicAdd(&statsp[256 + cb + n * 16], b0);
      }
    }
  }
}

// ---------- BatchNorm apply: read pre-norm bf16, write concat f32 + next-input bf16 ----------
__global__ __launch_bounds__(256) void norm_kernel(const u16* __restrict__ xp,
                                                   const float* __restrict__ stats,
                                                   const float* __restrict__ gamma,
                                                   const float* __restrict__ beta,
                                                   float* __restrict__ cout,
                                                   u16* __restrict__ xn) {
  const float invM = 1.0f / (float)N_NODES_C;
  int f0 = (threadIdx.x & 127) * 2;
  int half = threadIdx.x >> 7;
  float m0 = stats[f0] * invM, m1 = stats[f0 + 1] * invM;
  float v0 = stats[256 + f0] * invM - m0 * m0;
  float v1 = stats[256 + f0 + 1] * invM - m1 * m1;
  float sc0 = gamma[f0] * rsqrtf(v0 + 1e-5f);
  float sc1 = gamma[f0 + 1] * rsqrtf(v1 + 1e-5f);
  float bi0 = beta[f0] - m0 * sc0;
  float bi1 = beta[f0 + 1] - m1 * sc1;
  for (int r = blockIdx.x * 2 + half; r < N_NODES_C; r += 2 * gridDim.x) {
    u32 w = *reinterpret_cast<const u32*>(xp + (size_t)r * 256 + f0);
    float y0 = fmaf(bf2f((u16)w), sc0, bi0);
    float y1 = fmaf(bf2f((u16)(w >> 16)), sc1, bi1);
    float2 y; y.x = y0; y.y = y1;
    *reinterpret_cast<float2*>(cout + (size_t)r * 768 + f0) = y;
    *reinterpret_cast<u32*>(xn + (size_t)r * 256 + f0) =
        (u32)f2bf(y0) | ((u32)f2bf(y1) << 16);
  }
}

// ---------- global_add_pool (batch sorted -> per-graph segments) ----------
__global__ __launch_bounds__(256) void pool_kernel(const float* __restrict__ c, int ldc,
                                                   const int* __restrict__ batch,
                                                   float* __restrict__ outp) {
  __shared__ float red[1024];
  int g = blockIdx.x;
  int wid = threadIdx.x >> 6, lane = threadIdx.x & 63;
  int lo = 0, hi = N_NODES_C;
  while (lo < hi) { int mid = (lo + hi) >> 1; if (batch[mid] < g) lo = mid + 1; else hi = mid; }
  int start = lo;
  hi = N_NODES_C;
  while (lo < hi) { int mid = (lo + hi) >> 1; if (batch[mid] <= g) lo = mid + 1; else hi = mid; }
  int end = lo;
  float acc[4] = {0.f, 0.f, 0.f, 0.f};
  for (int r = start + wid; r < end; r += 4) {
    float4 v = *reinterpret_cast<const float4*>(c + (size_t)r * ldc + lane * 4);
    acc[0] += v.x; acc[1] += v.y; acc[2] += v.z; acc[3] += v.w;
  }
#pragma unroll
  for (int j = 0; j < 4; j++) red[wid * 256 + lane * 4 + j] = acc[j];
  __syncthreads();
  int f = threadIdx.x;
  float s = red[f] + red[256 + f] + red[512 + f] + red[768 + f];
  outp[(size_t)g * 256 + f] = s;
}

extern "C" void kernel_launch(void* const* d_in, const int* in_sizes, int n_in,
                              void* d_out, int out_size, void* d_ws, size_t ws_size,
                              hipStream_t stream) {
  (void)in_sizes; (void)n_in; (void)out_size; (void)ws_size;
  const float* x = (const float*)d_in[0];
  const int* ei = (const int*)d_in[1];
  const int* batch = (const int*)d_in[2];
  const float* W1_0 = (const float*)d_in[3];
  const float* W2_0 = (const float*)d_in[4];
  const float* gamma0 = (const float*)d_in[5];
  const float* beta0 = (const float*)d_in[6];
  const float* W1_1 = (const float*)d_in[7];
  const float* W2_1 = (const float*)d_in[8];
  const float* gamma1 = (const float*)d_in[9];
  const float* beta1 = (const float*)d_in[10];
  const float* W1_2 = (const float*)d_in[11];
  const float* W2_2 = (const float*)d_in[12];

  float* out = (float*)d_out;
  float* xpool = out;                                  // [256,256]
  float* concat = out + (size_t)N_GRAPHS_C * N_HID_C;  // [50000,768]

  char* ws = (char*)d_ws;
  size_t off = 0;
  auto alloc = [&](size_t bytes) -> char* {
    char* p = ws + off;
    off = (off + bytes + 255) & ~(size_t)255;
    return p;
  };
  int* cnt = (int*)alloc((N_NODES_C + 1) * 4);
  int* offs = (int*)alloc((N_NODES_C + 1) * 4);
  int* cursor = (int*)alloc(N_NODES_C * 4);
  int* incl = (int*)alloc(N_NODES_C * 4);
  int* bsum = (int*)alloc(64 * 4);
  int* csr = (int*)alloc((size_t)N_EDGES_C * 4);
  u16* xb = (u16*)alloc((size_t)N_NODES_C * N_FEAT_C * 2);
  u16* hin = (u16*)alloc((size_t)N_NODES_C * N_HID_C * 2);   // agg out; reused as xpre
  u16* tbuf = (u16*)alloc((size_t)N_NODES_C * N_HID_C * 2);
  u16* xn = (u16*)alloc((size_t)N_NODES_C * N_HID_C * 2);
  u16* w10t = (u16*)alloc((size_t)N_FEAT_C * N_HID_C * 2);
  u16* w20t = (u16*)alloc((size_t)N_HID_C * N_HID_C * 2);
  u16* w11t = (u16*)alloc((size_t)N_HID_C * N_HID_C * 2);
  u16* w21t = (u16*)alloc((size_t)N_HID_C * N_HID_C * 2);
  u16* w12t = (u16*)alloc((size_t)N_HID_C * N_HID_C * 2);
  u16* w22t = (u16*)alloc((size_t)N_HID_C * N_HID_C * 2);
  float* stats = (float*)alloc(512 * 4);

  const int* srcv = ei;
  const int* dstv = ei + N_EDGES_C;
  const int nb = (N_NODES_C + 1023) / 1024;  // 49
  const int ggrid = (N_NODES_C + 127) / 128; // 391

  hipMemsetAsync(cnt, 0, (N_NODES_C + 1) * 4, stream);

  convt_all_kernel<<<dim3(256, 6), 256, 0, stream>>>(W1_0, W2_0, W1_1, W2_1, W1_2, W2_2,
                                                     w10t, w20t, w11t, w21t, w12t, w22t);
  cvt4_kernel<<<(N_NODES_C * N_FEAT_C / 4 + 255) / 256, 256, 0, stream>>>(
      x, xb, N_NODES_C * N_FEAT_C / 4);

  count_kernel<<<(N_EDGES_C + 255) / 256, 256, 0, stream>>>(dstv, cnt, N_EDGES_C);
  scanA_kernel<<<nb, 1024, 0, stream>>>(cnt, incl, bsum, N_NODES_C);
  scanB_kernel<<<1, 64, 0, stream>>>(bsum, nb);
  scanC_kernel<<<nb, 1024, 0, stream>>>(cnt, incl, bsum, offs, cursor, N_NODES_C);
  fill_kernel<<<(N_EDGES_C + 255) / 256, 256, 0, stream>>>(srcv, dstv, cursor, csr, N_EDGES_C);

  // ---- Layer 0 ----
  agg_kernel<128><<<(N_NODES_C + 3) / 4, 256, 0, stream>>>(xb, offs, csr, hin);
  gemm_kernel<128, true, false, false><<<ggrid, 512, 0, stream>>>(hin, w10t, tbuf, nullptr, N_HID_C, nullptr);
  hipMemsetAsync(stats, 0, 512 * 4, stream);
  gemm_kernel<256, true, false, true><<<ggrid, 512, 0, stream>>>(tbuf, w20t, hin, nullptr, N_HID_C, stats);
  norm_kernel<<<2048, 256, 0, stream>>>(hin, stats, gamma0, beta0, concat + 0, xn);

  // ---- Layer 1 ----
  agg_kernel<256><<<(N_NODES_C + 3) / 4, 256, 0, stream>>>(xn, offs, csr, hin);
  gemm_kernel<256, true, false, false><<<ggrid, 512, 0, stream>>>(hin, w11t, tbuf, nullptr, N_HID_C, nullptr);
  hipMemsetAsync(stats, 0, 512 * 4, stream);
  gemm_kernel<256, true, false, true><<<ggrid, 512, 0, stream>>>(tbuf, w21t, hin, nullptr, N_HID_C, stats);
  norm_kernel<<<2048, 256, 0, stream>>>(hin, stats, gamma1, beta1, concat + 256, xn);

  // ---- Layer 2 (no relu, no BN) ----
  agg_kernel<256><<<(N_NODES_C + 3) / 4, 256, 0, stream>>>(xn, offs, csr, hin);
  gemm_kernel<256, true, false, false><<<ggrid, 512, 0, stream>>>(hin, w12t, tbuf, nullptr, N_HID_C, nullptr);
  gemm_kernel<256, false, true, false><<<ggrid, 512, 0, stream>>>(tbuf, w22t, nullptr, concat + 512, 768, nullptr);

  // ---- pool ----
  pool_kernel<<<N_GRAPHS_C, 256, 0, stream>>>(concat + 512, 768, batch, xpool);
}